// Round 1
// baseline (253.924 us; speedup 1.0000x reference)
//
#include <hip/hip_runtime.h>

// Reblur_Net: 3 recurrent modulated deformable convs (DCNv2), stride1/pad1,
// C=O=3, K=3, B=4, H=W=512. out = (sharp + f1 + f2 + f3) / 4.

#define HH 512
#define WW 512
#define BATCH 4
#define CCH 3
#define NKK 9
#define HWSZ (HH * WW)

// FIRST: also write out = (sharp + f)*0.25 (overwrite -> deterministic replay).
// WRITE_DST: store f for the next recurrence.
template <bool FIRST, bool WRITE_DST>
__global__ __launch_bounds__(256) void dcn_kernel(
    const float* __restrict__ src,     // [B,3,H,W] current features
    const float* __restrict__ motion,  // [B,27,H,W] (dy,dx)x9 interleaved, then 9 masks
    const float* __restrict__ wgt,     // 81 floats: [o][c][k]
    const float* __restrict__ bias,    // 3 floats
    float* __restrict__ dst,           // [B,3,H,W] f_i (if WRITE_DST)
    const float* __restrict__ sharp,   // [B,3,H,W] (if FIRST)
    float* __restrict__ out)           // [B,3,H,W]
{
    __shared__ float sw[84];
    const int t = threadIdx.x;
    if (t < 84) sw[t] = (t < 81) ? wgt[t] : bias[t - 81];
    __syncthreads();

    const int idx = blockIdx.x * 256 + t;            // over B*H*W (exact multiple)
    const int x = idx & (WW - 1);
    const int y = (idx >> 9) & (HH - 1);
    const int b = idx >> 18;
    const int p = y * WW + x;

    const float* mb = motion + (size_t)b * 27 * HWSZ + p;
    const float* srcb = src + (size_t)b * CCH * HWSZ;

    float acc0 = sw[81], acc1 = sw[82], acc2 = sw[83];

#pragma unroll
    for (int k = 0; k < NKK; ++k) {
        const float dy = mb[(2 * k) * HWSZ];
        const float dx = mb[(2 * k + 1) * HWSZ];
        const float m  = mb[(18 + k) * HWSZ];

        const float py = (float)(y + k / 3 - 1) + dy;
        const float px = (float)(x + k % 3 - 1) + dx;
        const float y0f = floorf(py);
        const float x0f = floorf(px);
        const float wy = py - y0f;
        const float wx = px - x0f;

        const bool vy0 = (y0f >= 0.f) && (y0f <= (float)(HH - 1));
        const bool vy1 = (y0f + 1.f >= 0.f) && (y0f + 1.f <= (float)(HH - 1));
        const bool vx0 = (x0f >= 0.f) && (x0f <= (float)(WW - 1));
        const bool vx1 = (x0f + 1.f >= 0.f) && (x0f + 1.f <= (float)(WW - 1));

        const int iy0 = (int)fminf(fmaxf(y0f, 0.f), (float)(HH - 1));
        const int iy1 = (int)fminf(fmaxf(y0f + 1.f, 0.f), (float)(HH - 1));
        const int ix0 = (int)fminf(fmaxf(x0f, 0.f), (float)(WW - 1));
        const int ix1 = (int)fminf(fmaxf(x0f + 1.f, 0.f), (float)(WW - 1));

        const float w00 = (vy0 && vx0) ? (1.f - wy) * (1.f - wx) * m : 0.f;
        const float w01 = (vy0 && vx1) ? (1.f - wy) * wx * m : 0.f;
        const float w10 = (vy1 && vx0) ? wy * (1.f - wx) * m : 0.f;
        const float w11 = (vy1 && vx1) ? wy * wx * m : 0.f;

        const int i00 = iy0 * WW + ix0;
        const int i01 = iy0 * WW + ix1;
        const int i10 = iy1 * WW + ix0;
        const int i11 = iy1 * WW + ix1;

#pragma unroll
        for (int c = 0; c < CCH; ++c) {
            const float* ch = srcb + c * HWSZ;
            const float val = w00 * ch[i00] + w01 * ch[i01] +
                              w10 * ch[i10] + w11 * ch[i11];
            acc0 += sw[(0 * 3 + c) * 9 + k] * val;
            acc1 += sw[(1 * 3 + c) * 9 + k] * val;
            acc2 += sw[(2 * 3 + c) * 9 + k] * val;
        }
    }

    const size_t ob = (size_t)b * CCH * HWSZ + p;
    if (WRITE_DST) {
        dst[ob] = acc0;
        dst[ob + HWSZ] = acc1;
        dst[ob + 2 * HWSZ] = acc2;
    }
    if (FIRST) {
        out[ob] = (sharp[ob] + acc0) * 0.25f;
        out[ob + HWSZ] = (sharp[ob + HWSZ] + acc1) * 0.25f;
        out[ob + 2 * HWSZ] = (sharp[ob + 2 * HWSZ] + acc2) * 0.25f;
    } else {
        out[ob] += acc0 * 0.25f;
        out[ob + HWSZ] += acc1 * 0.25f;
        out[ob + 2 * HWSZ] += acc2 * 0.25f;
    }
}

extern "C" void kernel_launch(void* const* d_in, const int* in_sizes, int n_in,
                              void* d_out, int out_size, void* d_ws, size_t ws_size,
                              hipStream_t stream) {
    const float* sharp  = (const float*)d_in[0];
    const float* motion = (const float*)d_in[1];
    const float* wts    = (const float*)d_in[2];  // [3,3,3,3,3] = 3 x 81
    const float* bias   = (const float*)d_in[3];  // [3,3]
    float* out = (float*)d_out;

    const size_t img = (size_t)BATCH * CCH * HWSZ;  // 3,145,728 floats
    float* f1 = (float*)d_ws;
    float* f2 = f1 + img;

    const dim3 grid(BATCH * HWSZ / 256);
    const dim3 block(256);

    dcn_kernel<true, true><<<grid, block, 0, stream>>>(
        sharp, motion, wts, bias, f1, sharp, out);
    dcn_kernel<false, true><<<grid, block, 0, stream>>>(
        f1, motion, wts + 81, bias + 3, f2, nullptr, out);
    dcn_kernel<false, false><<<grid, block, 0, stream>>>(
        f2, motion, wts + 162, bias + 6, nullptr, nullptr, out);
}

// Round 2
// 176.319 us; speedup vs baseline: 1.4401x; 1.4401x over previous
//
#include <hip/hip_runtime.h>

// Reblur_Net: 3 recurrent modulated deformable convs (DCNv2), stride1/pad1,
// C=O=3, K=3, B=4, H=W=512. out = (sharp + f1 + f2 + f3) / 4.
//
// Feature maps kept in interleaved [B,H,W,4] float4 layout so each bilinear
// corner is ONE 16B gather (3 channels at once) instead of three 4B gathers.

#define HH 512
#define WW 512
#define BATCH 4
#define CCH 3
#define NKK 9
#define HWSZ (HH * WW)

__global__ __launch_bounds__(256) void transpose_kernel(
    const float* __restrict__ sharp, float4* __restrict__ dst)
{
    const int idx = blockIdx.x * 256 + threadIdx.x;  // over B*H*W
    const int b = idx >> 18;
    const int p = idx & (HWSZ - 1);
    const float* s = sharp + (size_t)b * CCH * HWSZ + p;
    dst[idx] = make_float4(s[0], s[HWSZ], s[2 * HWSZ], 0.f);
}

// FIRST: out = (sharp_center + f)*0.25 (overwrite -> deterministic replay).
// WRITE_DST: store f (interleaved) for the next recurrence.
template <bool FIRST, bool WRITE_DST>
__global__ __launch_bounds__(256) void dcn_kernel(
    const float4* __restrict__ src,    // [B,H,W] float4 features (c0,c1,c2,-)
    const float* __restrict__ motion,  // [B,27,H,W] (dy,dx)x9, then 9 masks
    const float* __restrict__ wgt,     // 81 floats: [o][c][k]
    const float* __restrict__ bias,    // 3 floats
    float4* __restrict__ dst,          // [B,H,W] f_i (if WRITE_DST)
    float* __restrict__ out)           // [B,3,H,W] planar
{
    __shared__ float sw[84];
    const int t = threadIdx.x;
    if (t < 84) sw[t] = (t < 81) ? wgt[t] : bias[t - 81];
    __syncthreads();

    const int idx = blockIdx.x * 256 + t;            // over B*H*W
    const int x = idx & (WW - 1);
    const int y = (idx >> 9) & (HH - 1);
    const int b = idx >> 18;
    const int p = y * WW + x;

    const float* mb = motion + (size_t)b * 27 * HWSZ + p;
    const float4* s4 = src + (size_t)b * HWSZ;

    float acc0 = sw[81], acc1 = sw[82], acc2 = sw[83];

#pragma unroll
    for (int k = 0; k < NKK; ++k) {
        const float dy = mb[(2 * k) * HWSZ];
        const float dx = mb[(2 * k + 1) * HWSZ];
        const float m  = mb[(18 + k) * HWSZ];

        const float py = (float)(y + k / 3 - 1) + dy;
        const float px = (float)(x + k % 3 - 1) + dx;
        const float y0f = floorf(py);
        const float x0f = floorf(px);
        const float wy = py - y0f;
        const float wx = px - x0f;

        const bool vy0 = (y0f >= 0.f) && (y0f <= (float)(HH - 1));
        const bool vy1 = (y0f >= -1.f) && (y0f <= (float)(HH - 2));
        const bool vx0 = (x0f >= 0.f) && (x0f <= (float)(WW - 1));
        const bool vx1 = (x0f >= -1.f) && (x0f <= (float)(WW - 2));

        const int iy0 = (int)fminf(fmaxf(y0f, 0.f), (float)(HH - 1));
        const int iy1 = (int)fminf(fmaxf(y0f + 1.f, 0.f), (float)(HH - 1));
        const int ix0 = (int)fminf(fmaxf(x0f, 0.f), (float)(WW - 1));
        const int ix1 = (int)fminf(fmaxf(x0f + 1.f, 0.f), (float)(WW - 1));

        const float w00 = (vy0 && vx0) ? (1.f - wy) * (1.f - wx) * m : 0.f;
        const float w01 = (vy0 && vx1) ? (1.f - wy) * wx * m : 0.f;
        const float w10 = (vy1 && vx0) ? wy * (1.f - wx) * m : 0.f;
        const float w11 = (vy1 && vx1) ? wy * wx * m : 0.f;

        const float4 v00 = s4[iy0 * WW + ix0];
        const float4 v01 = s4[iy0 * WW + ix1];
        const float4 v10 = s4[iy1 * WW + ix0];
        const float4 v11 = s4[iy1 * WW + ix1];

        const float val0 = w00 * v00.x + w01 * v01.x + w10 * v10.x + w11 * v11.x;
        const float val1 = w00 * v00.y + w01 * v01.y + w10 * v10.y + w11 * v11.y;
        const float val2 = w00 * v00.z + w01 * v01.z + w10 * v10.z + w11 * v11.z;

        acc0 += sw[(0 * 3 + 0) * 9 + k] * val0 + sw[(0 * 3 + 1) * 9 + k] * val1 + sw[(0 * 3 + 2) * 9 + k] * val2;
        acc1 += sw[(1 * 3 + 0) * 9 + k] * val0 + sw[(1 * 3 + 1) * 9 + k] * val1 + sw[(1 * 3 + 2) * 9 + k] * val2;
        acc2 += sw[(2 * 3 + 0) * 9 + k] * val0 + sw[(2 * 3 + 1) * 9 + k] * val1 + sw[(2 * 3 + 2) * 9 + k] * val2;
    }

    if (WRITE_DST) {
        dst[(size_t)b * HWSZ + p] = make_float4(acc0, acc1, acc2, 0.f);
    }

    const size_t ob = (size_t)b * CCH * HWSZ + p;
    if (FIRST) {
        const float4 sc = s4[p];  // src == sharp_interleaved in pass 1
        out[ob] = (sc.x + acc0) * 0.25f;
        out[ob + HWSZ] = (sc.y + acc1) * 0.25f;
        out[ob + 2 * HWSZ] = (sc.z + acc2) * 0.25f;
    } else {
        out[ob] += acc0 * 0.25f;
        out[ob + HWSZ] += acc1 * 0.25f;
        out[ob + 2 * HWSZ] += acc2 * 0.25f;
    }
}

extern "C" void kernel_launch(void* const* d_in, const int* in_sizes, int n_in,
                              void* d_out, int out_size, void* d_ws, size_t ws_size,
                              hipStream_t stream) {
    const float* sharp  = (const float*)d_in[0];
    const float* motion = (const float*)d_in[1];
    const float* wts    = (const float*)d_in[2];  // 3 x 81
    const float* bias   = (const float*)d_in[3];  // 3 x 3
    float* out = (float*)d_out;

    float4* bufA = (float4*)d_ws;                 // 16.8 MB each
    float4* bufB = bufA + (size_t)BATCH * HWSZ;

    const dim3 grid(BATCH * HWSZ / 256);
    const dim3 block(256);

    // sharp [B,3,H,W] -> interleaved float4 bufA
    transpose_kernel<<<grid, block, 0, stream>>>(sharp, bufA);
    // pass 1: reads bufA, writes f1 -> bufB, out = (sharp + f1)/4
    dcn_kernel<true, true><<<grid, block, 0, stream>>>(
        bufA, motion, wts, bias, bufB, out);
    // pass 2: reads bufB, writes f2 -> bufA (sharp copy no longer needed)
    dcn_kernel<false, true><<<grid, block, 0, stream>>>(
        bufB, motion, wts + 81, bias + 3, bufA, out);
    // pass 3: reads bufA, out += f3/4
    dcn_kernel<false, false><<<grid, block, 0, stream>>>(
        bufA, motion, wts + 162, bias + 6, nullptr, out);
}

// Round 3
// 138.529 us; speedup vs baseline: 1.8330x; 1.2728x over previous
//
#include <hip/hip_runtime.h>
#include <hip/hip_fp16.h>

// Reblur_Net: 3 recurrent modulated DCNv2 passes, C=O=3, K=3, B=4, H=W=512.
// out = (sharp + f1 + f2 + f3) / 4.
//
// Features stored as half4 (8 B/px, c0,c1,c2,pad). Both corners of a bilinear
// row are one 16B dwordx4 gather (AMD global loads need only 4B alignment).
// 2 pixels per thread -> motion loads are dwordx2. ~34 VMEM inst/pixel.

#define HH 512
#define WW 512
#define BATCH 4
#define HWSZ (HH * WW)
#define PAIRS_PER_IMG (HWSZ / 2)      // 131072 = 2^17

union U4 { uint4 u; __half2 h[4]; };

__global__ __launch_bounds__(256) void to_half_kernel(
    const float* __restrict__ sharp, uint4* __restrict__ dst)
{
    const int i = blockIdx.x * 256 + threadIdx.x;   // pair index over B*HWSZ/2
    const int b = i >> 17;
    const int p = (i & (PAIRS_PER_IMG - 1)) * 2;
    const float* s = sharp + (size_t)b * 3 * HWSZ + p;
    const float2 c0 = *(const float2*)(s);
    const float2 c1 = *(const float2*)(s + HWSZ);
    const float2 c2 = *(const float2*)(s + 2 * HWSZ);
    U4 o;
    o.h[0] = __float22half2_rn(make_float2(c0.x, c1.x));
    o.h[1] = __float22half2_rn(make_float2(c2.x, 0.f));
    o.h[2] = __float22half2_rn(make_float2(c0.y, c1.y));
    o.h[3] = __float22half2_rn(make_float2(c2.y, 0.f));
    dst[i] = o.u;
}

// Bilinear sample of 3 channels at (py,px) with modulation m, zero outside.
__device__ __forceinline__ void bilinear3(const char* __restrict__ sb,
                                          float py, float px, float m,
                                          float& o0, float& o1, float& o2)
{
    const float y0f = floorf(py), x0f = floorf(px);
    const float wy = py - y0f, wx = px - x0f;
    const bool vy0 = (y0f >= 0.f) && (y0f <= 511.f);
    const bool vy1 = (y0f >= -1.f) && (y0f <= 510.f);
    const bool vx0 = (x0f >= 0.f) && (x0f <= 511.f);
    const bool vx1 = (x0f >= -1.f) && (x0f <= 510.f);
    const int iy0 = (int)fminf(fmaxf(y0f, 0.f), 511.f);
    const int iy1 = (int)fminf(fmaxf(y0f + 1.f, 0.f), 511.f);
    const int ix0 = (int)fminf(fmaxf(x0f, 0.f), 511.f);
    const int ix1 = (int)fminf(fmaxf(x0f + 1.f, 0.f), 511.f);
    const int lc  = (int)fminf(fmaxf(x0f, 0.f), 510.f);   // pair base column
    const int s0 = ix0 - lc;    // slot (0/1) of the x0 corner
    const int s1 = ix1 - lc;    // slot of the x1 corner

    float w00 = (vy0 && vx0) ? (1.f - wy) * (1.f - wx) * m : 0.f;
    float w01 = (vy0 && vx1) ? (1.f - wy) * wx * m : 0.f;
    float w10 = (vy1 && vx0) ? wy * (1.f - wx) * m : 0.f;
    float w11 = (vy1 && vx1) ? wy * wx * m : 0.f;

    // Blend corner weights onto the two loaded slots (handles clamp cases).
    const float wlo0 = s0 ? 0.f : (s1 ? w00 : w00 + w01);
    const float whi0 = s1 ? (s0 ? w00 + w01 : w01) : 0.f;
    const float wlo1 = s0 ? 0.f : (s1 ? w10 : w10 + w11);
    const float whi1 = s1 ? (s0 ? w10 + w11 : w11) : 0.f;

    U4 ra, rb;
    ra.u = *(const uint4*)(sb + (size_t)(iy0 * WW + lc) * 8);
    rb.u = *(const uint4*)(sb + (size_t)(iy1 * WW + lc) * 8);
    const float2 aL = __half22float2(ra.h[0]);   // row0 lo px: c0,c1
    const float2 aLz = __half22float2(ra.h[1]);  // row0 lo px: c2,-
    const float2 aH = __half22float2(ra.h[2]);   // row0 hi px: c0,c1
    const float2 aHz = __half22float2(ra.h[3]);
    const float2 bL = __half22float2(rb.h[0]);
    const float2 bLz = __half22float2(rb.h[1]);
    const float2 bH = __half22float2(rb.h[2]);
    const float2 bHz = __half22float2(rb.h[3]);

    o0 = wlo0 * aL.x + whi0 * aH.x + wlo1 * bL.x + whi1 * bH.x;
    o1 = wlo0 * aL.y + whi0 * aH.y + wlo1 * bL.y + whi1 * bH.y;
    o2 = wlo0 * aLz.x + whi0 * aHz.x + wlo1 * bLz.x + whi1 * bHz.x;
}

template <bool FIRST, bool WRITE_DST>
__global__ __launch_bounds__(256) void dcn_kernel(
    const uint4* __restrict__ src,     // [B][HWSZ/2] packed half4 pairs
    const float* __restrict__ motion,  // [B,27,H,W]
    const float* __restrict__ wgt,     // 81 floats [o][c][k]
    const float* __restrict__ bias,    // 3 floats
    uint4* __restrict__ dst,           // packed half4 pairs (if WRITE_DST)
    float* __restrict__ out)           // [B,3,H,W] planar fp32
{
    __shared__ float sw[84];
    const int t = threadIdx.x;
    if (t < 84) sw[t] = (t < 81) ? wgt[t] : bias[t - 81];
    __syncthreads();

    const int i = blockIdx.x * 256 + t;            // pair index
    const int b = i >> 17;
    const int r = i & (PAIRS_PER_IMG - 1);
    const int y = r >> 8;
    const int x0 = (r & 255) * 2;
    const int p = y * WW + x0;

    const float* mb = motion + (size_t)b * 27 * HWSZ + p;
    const char* sb = (const char*)(src + (size_t)b * (HWSZ / 2));

    float a00 = sw[81], a01 = sw[82], a02 = sw[83];   // pixel A
    float a10 = sw[81], a11 = sw[82], a12 = sw[83];   // pixel B

#pragma unroll
    for (int k = 0; k < 9; ++k) {
        const float2 dy = *(const float2*)(mb + (size_t)(2 * k) * HWSZ);
        const float2 dx = *(const float2*)(mb + (size_t)(2 * k + 1) * HWSZ);
        const float2 m  = *(const float2*)(mb + (size_t)(18 + k) * HWSZ);
        const float ky = (float)(y + k / 3 - 1);
        const float kx = (float)(x0 + k % 3 - 1);

        float v0, v1, v2;
        bilinear3(sb, ky + dy.x, kx + dx.x, m.x, v0, v1, v2);
        a00 += sw[0 * 9 + k] * v0 + sw[1 * 9 + k] * v1 + sw[2 * 9 + k] * v2;
        a01 += sw[3 * 9 + k] * v0 + sw[4 * 9 + k] * v1 + sw[5 * 9 + k] * v2;
        a02 += sw[6 * 9 + k] * v0 + sw[7 * 9 + k] * v1 + sw[8 * 9 + k] * v2;

        float u0, u1, u2;
        bilinear3(sb, ky + dy.y, kx + 1.f + dx.y, m.y, u0, u1, u2);
        a10 += sw[0 * 9 + k] * u0 + sw[1 * 9 + k] * u1 + sw[2 * 9 + k] * u2;
        a11 += sw[3 * 9 + k] * u0 + sw[4 * 9 + k] * u1 + sw[5 * 9 + k] * u2;
        a12 += sw[6 * 9 + k] * u0 + sw[7 * 9 + k] * u1 + sw[8 * 9 + k] * u2;
    }

    if (WRITE_DST) {
        U4 o;
        o.h[0] = __float22half2_rn(make_float2(a00, a01));
        o.h[1] = __float22half2_rn(make_float2(a02, 0.f));
        o.h[2] = __float22half2_rn(make_float2(a10, a11));
        o.h[3] = __float22half2_rn(make_float2(a12, 0.f));
        dst[i] = o.u;
    }

    const size_t ob = (size_t)b * 3 * HWSZ + p;
    if (FIRST) {
        U4 c;
        c.u = *(const uint4*)(sb + (size_t)p * 8);   // center pair (16B aligned)
        const float2 pA01 = __half22float2(c.h[0]);
        const float2 pA2 = __half22float2(c.h[1]);
        const float2 pB01 = __half22float2(c.h[2]);
        const float2 pB2 = __half22float2(c.h[3]);
        *(float2*)(out + ob) = make_float2((pA01.x + a00) * 0.25f, (pB01.x + a10) * 0.25f);
        *(float2*)(out + ob + HWSZ) = make_float2((pA01.y + a01) * 0.25f, (pB01.y + a11) * 0.25f);
        *(float2*)(out + ob + 2 * HWSZ) = make_float2((pA2.x + a02) * 0.25f, (pB2.x + a12) * 0.25f);
    } else {
        float2 o0 = *(float2*)(out + ob);
        float2 o1 = *(float2*)(out + ob + HWSZ);
        float2 o2 = *(float2*)(out + ob + 2 * HWSZ);
        o0.x += a00 * 0.25f; o0.y += a10 * 0.25f;
        o1.x += a01 * 0.25f; o1.y += a11 * 0.25f;
        o2.x += a02 * 0.25f; o2.y += a12 * 0.25f;
        *(float2*)(out + ob) = o0;
        *(float2*)(out + ob + HWSZ) = o1;
        *(float2*)(out + ob + 2 * HWSZ) = o2;
    }
}

extern "C" void kernel_launch(void* const* d_in, const int* in_sizes, int n_in,
                              void* d_out, int out_size, void* d_ws, size_t ws_size,
                              hipStream_t stream) {
    const float* sharp  = (const float*)d_in[0];
    const float* motion = (const float*)d_in[1];
    const float* wts    = (const float*)d_in[2];  // 3 x 81
    const float* bias   = (const float*)d_in[3];  // 3 x 3
    float* out = (float*)d_out;

    const size_t npairs = (size_t)BATCH * PAIRS_PER_IMG;   // 524288
    uint4* bufA = (uint4*)d_ws;            // 8.4 MB each
    uint4* bufB = bufA + npairs;

    const dim3 grid(npairs / 256);         // 2048 blocks
    const dim3 block(256);

    to_half_kernel<<<grid, block, 0, stream>>>(sharp, bufA);
    dcn_kernel<true, true><<<grid, block, 0, stream>>>(
        bufA, motion, wts, bias, bufB, out);
    dcn_kernel<false, true><<<grid, block, 0, stream>>>(
        bufB, motion, wts + 81, bias + 3, bufA, out);
    dcn_kernel<false, false><<<grid, block, 0, stream>>>(
        bufA, motion, wts + 162, bias + 6, nullptr, out);
}

// Round 4
// 119.488 us; speedup vs baseline: 2.1251x; 1.1594x over previous
//
#include <hip/hip_runtime.h>
#include <hip/hip_fp16.h>

// Reblur_Net: 3 recurrent modulated DCNv2 passes, C=O=3, K=3, B=4, H=W=512.
// out = (sharp + f1 + f2 + f3) / 4.
//
// Features as half4 (8 B/px). Both corners of a bilinear row = one 16B gather.
// Motion for each 256-px strip is DMA'd into LDS via global_load_lds (async,
// no VGPR cost), so the per-thread critical path is ds_read -> gather -> FMA.

#define HH 512
#define WW 512
#define BATCH 4
#define HWSZ (HH * WW)
#define PAIRS_PER_IMG (HWSZ / 2)

union U4 { uint4 u; __half2 h[4]; };
union U2 { uint2 u; __half2 h[2]; };

typedef const __attribute__((address_space(1))) void* gas_t;
typedef __attribute__((address_space(3))) void* las_t;

__global__ __launch_bounds__(256) void to_half_kernel(
    const float* __restrict__ sharp, uint4* __restrict__ dst)
{
    const int i = blockIdx.x * 256 + threadIdx.x;   // pair index over B*HWSZ/2
    const int b = i >> 17;
    const int p = (i & (PAIRS_PER_IMG - 1)) * 2;
    const float* s = sharp + (size_t)b * 3 * HWSZ + p;
    const float2 c0 = *(const float2*)(s);
    const float2 c1 = *(const float2*)(s + HWSZ);
    const float2 c2 = *(const float2*)(s + 2 * HWSZ);
    U4 o;
    o.h[0] = __float22half2_rn(make_float2(c0.x, c1.x));
    o.h[1] = __float22half2_rn(make_float2(c2.x, 0.f));
    o.h[2] = __float22half2_rn(make_float2(c0.y, c1.y));
    o.h[3] = __float22half2_rn(make_float2(c2.y, 0.f));
    dst[i] = o.u;
}

// Bilinear sample of 3 channels at (py,px), modulation m, zero outside.
__device__ __forceinline__ void bilinear3(const char* __restrict__ sb,
                                          float py, float px, float m,
                                          float& o0, float& o1, float& o2)
{
    const float y0f = floorf(py), x0f = floorf(px);
    const float wy = py - y0f, wx = px - x0f;
    const bool vy0 = (y0f >= 0.f) && (y0f <= 511.f);
    const bool vy1 = (y0f >= -1.f) && (y0f <= 510.f);
    const bool vx0 = (x0f >= 0.f) && (x0f <= 511.f);
    const bool vx1 = (x0f >= -1.f) && (x0f <= 510.f);
    const int iy0 = (int)fminf(fmaxf(y0f, 0.f), 511.f);
    const int iy1 = (int)fminf(fmaxf(y0f + 1.f, 0.f), 511.f);
    const int ix0 = (int)fminf(fmaxf(x0f, 0.f), 511.f);
    const int ix1 = (int)fminf(fmaxf(x0f + 1.f, 0.f), 511.f);
    const int lc  = (int)fminf(fmaxf(x0f, 0.f), 510.f);   // pair base column
    const int s0 = ix0 - lc;
    const int s1 = ix1 - lc;

    const float w00 = (vy0 && vx0) ? (1.f - wy) * (1.f - wx) * m : 0.f;
    const float w01 = (vy0 && vx1) ? (1.f - wy) * wx * m : 0.f;
    const float w10 = (vy1 && vx0) ? wy * (1.f - wx) * m : 0.f;
    const float w11 = (vy1 && vx1) ? wy * wx * m : 0.f;

    // Blend corner weights onto the two loaded pixel slots (clamp-safe).
    const float wlo0 = s0 ? 0.f : (s1 ? w00 : w00 + w01);
    const float whi0 = s1 ? (s0 ? w00 + w01 : w01) : 0.f;
    const float wlo1 = s0 ? 0.f : (s1 ? w10 : w10 + w11);
    const float whi1 = s1 ? (s0 ? w10 + w11 : w11) : 0.f;

    U4 ra, rb;
    ra.u = *(const uint4*)(sb + (size_t)(iy0 * WW + lc) * 8);
    rb.u = *(const uint4*)(sb + (size_t)(iy1 * WW + lc) * 8);
    const float2 aL = __half22float2(ra.h[0]);
    const float2 aLz = __half22float2(ra.h[1]);
    const float2 aH = __half22float2(ra.h[2]);
    const float2 aHz = __half22float2(ra.h[3]);
    const float2 bL = __half22float2(rb.h[0]);
    const float2 bLz = __half22float2(rb.h[1]);
    const float2 bH = __half22float2(rb.h[2]);
    const float2 bHz = __half22float2(rb.h[3]);

    o0 = wlo0 * aL.x + whi0 * aH.x + wlo1 * bL.x + whi1 * bH.x;
    o1 = wlo0 * aL.y + whi0 * aH.y + wlo1 * bL.y + whi1 * bH.y;
    o2 = wlo0 * aLz.x + whi0 * aHz.x + wlo1 * bLz.x + whi1 * bHz.x;
}

template <bool FIRST, bool WRITE_DST>
__global__ __launch_bounds__(256) void dcn_kernel(
    const uint2* __restrict__ src,     // [B][HWSZ] half4 px
    const float* __restrict__ motion,  // [B,27,H,W]
    const float* __restrict__ wgt,     // 81 floats [o][c][k]
    const float* __restrict__ bias,    // 3 floats
    uint2* __restrict__ dst,           // half4 px (if WRITE_DST)
    float* __restrict__ out)           // [B,3,H,W] planar fp32
{
    __shared__ float mlds[27][256];    // motion slice for this 256-px strip
    __shared__ float sw[84];

    const int t = threadIdx.x;
    const int blk = blockIdx.x;            // 4096 blocks
    const int b = blk >> 10;               // 1024 strips per image
    const int pbase = (blk & 1023) * 256;
    const int p = pbase + t;
    const int y = p >> 9;
    const int x = p & 511;

    if (t < 84) sw[t] = (t < 81) ? wgt[t] : bias[t - 81];

    // Async DMA: motion[plane][pbase..pbase+255] -> mlds[plane][:].
    // One wave handles one plane per round (LDS dest = uniform base + lane*16).
    {
        const int w = t >> 6, lane = t & 63;
        const float* mbase = motion + (size_t)b * 27 * HWSZ + pbase;
#pragma unroll
        for (int r = 0; r < 7; ++r) {
            const int plane = r * 4 + w;
            if (plane < 27) {
                const float* gsrc = mbase + (size_t)plane * HWSZ + lane * 4;
                __builtin_amdgcn_global_load_lds((gas_t)gsrc,
                                                 (las_t)&mlds[plane][0],
                                                 16, 0, 0);
            }
        }
    }
    __syncthreads();   // drains vmcnt + lgkmcnt

    const char* sb = (const char*)src + (size_t)b * HWSZ * 8;

    float acc0 = sw[81], acc1 = sw[82], acc2 = sw[83];

#pragma unroll
    for (int k = 0; k < 9; ++k) {
        const float dy = mlds[2 * k][t];
        const float dx = mlds[2 * k + 1][t];
        const float m  = mlds[18 + k][t];
        const float py = (float)(y + k / 3 - 1) + dy;
        const float px = (float)(x + k % 3 - 1) + dx;

        float v0, v1, v2;
        bilinear3(sb, py, px, m, v0, v1, v2);
        acc0 += sw[0 * 9 + k] * v0 + sw[1 * 9 + k] * v1 + sw[2 * 9 + k] * v2;
        acc1 += sw[3 * 9 + k] * v0 + sw[4 * 9 + k] * v1 + sw[5 * 9 + k] * v2;
        acc2 += sw[6 * 9 + k] * v0 + sw[7 * 9 + k] * v1 + sw[8 * 9 + k] * v2;
    }

    if (WRITE_DST) {
        U2 o;
        o.h[0] = __float22half2_rn(make_float2(acc0, acc1));
        o.h[1] = __float22half2_rn(make_float2(acc2, 0.f));
        dst[(size_t)b * HWSZ + p] = o.u;
    }

    const size_t ob = (size_t)b * 3 * HWSZ + p;
    if (FIRST) {
        U2 c;
        c.u = *(const uint2*)(sb + (size_t)p * 8);
        const float2 s01 = __half22float2(c.h[0]);
        const float2 s2 = __half22float2(c.h[1]);
        out[ob] = (s01.x + acc0) * 0.25f;
        out[ob + HWSZ] = (s01.y + acc1) * 0.25f;
        out[ob + 2 * HWSZ] = (s2.x + acc2) * 0.25f;
    } else {
        out[ob] += acc0 * 0.25f;
        out[ob + HWSZ] += acc1 * 0.25f;
        out[ob + 2 * HWSZ] += acc2 * 0.25f;
    }
}

extern "C" void kernel_launch(void* const* d_in, const int* in_sizes, int n_in,
                              void* d_out, int out_size, void* d_ws, size_t ws_size,
                              hipStream_t stream) {
    const float* sharp  = (const float*)d_in[0];
    const float* motion = (const float*)d_in[1];
    const float* wts    = (const float*)d_in[2];  // 3 x 81
    const float* bias   = (const float*)d_in[3];  // 3 x 3
    float* out = (float*)d_out;

    uint2* bufA = (uint2*)d_ws;                   // 8.4 MB each
    uint2* bufB = bufA + (size_t)BATCH * HWSZ;

    const dim3 block(256);
    const dim3 gridT(BATCH * PAIRS_PER_IMG / 256);   // 2048
    const dim3 gridD(BATCH * HWSZ / 256);            // 4096

    to_half_kernel<<<gridT, block, 0, stream>>>(sharp, (uint4*)bufA);
    dcn_kernel<true, true><<<gridD, block, 0, stream>>>(
        bufA, motion, wts, bias, bufB, out);
    dcn_kernel<false, true><<<gridD, block, 0, stream>>>(
        bufB, motion, wts + 81, bias + 3, bufA, out);
    dcn_kernel<false, false><<<gridD, block, 0, stream>>>(
        bufA, motion, wts + 162, bias + 6, nullptr, out);
}